// Round 4
// baseline (93.277 us; speedup 1.0000x reference)
//
#include <hip/hip_runtime.h>
#include <math.h>

#define TWO_PI 6.283185307179586f

// workspace layout (floats)
#define OFF_ET   0ull          // energy transposed [be][f][4096]; later reused for frames
#define OFF_E    8388608ull    // spectra E [be][f][2049] float2
#define OFF_MAXP 16781312ull   // 1024 partial maxima
#define OFF_Z    16782336ull   // packed Z' [be][f][2048] float2

__device__ __forceinline__ int swz(int n) { return n ^ ((n >> 5) & 31); }

// position of natural index k after DIF with radices [2,4,4,4,4,4]
__device__ __forceinline__ int permf(int k) {
    return ((k & 1) << 10) | (((k >> 1) & 3) << 8) | (((k >> 3) & 3) << 6)
         | (((k >> 5) & 3) << 4) | (((k >> 7) & 3) << 2) | ((k >> 9) & 3);
}

__device__ __forceinline__ void r4_fwd(float* cr, float* ci, int j, int h, float ang) {
    int p0 = swz(j), p1 = swz(j + h), p2 = swz(j + 2 * h), p3 = swz(j + 3 * h);
    float ar = cr[p0], ai = ci[p0];
    float br = cr[p1], bi = ci[p1];
    float crr = cr[p2], cri = ci[p2];
    float drr = cr[p3], dri = ci[p3];
    float u0r = ar + crr, u0i = ai + cri;
    float u1r = ar - crr, u1i = ai - cri;
    float u2r = br + drr, u2i = bi + dri;
    float u3r = br - drr, u3i = bi - dri;
    float s1, c1; __sincosf(ang, &s1, &c1);
    float c2 = c1 * c1 - s1 * s1, s2 = 2.f * c1 * s1;
    float c3 = c1 * c2 - s1 * s2, s3 = s1 * c2 + c1 * s2;
    cr[p0] = u0r + u2r; ci[p0] = u0i + u2i;
    float z1r = u1r + u3i, z1i = u1i - u3r;            // u1 - i*u3
    cr[p1] = z1r * c1 + z1i * s1; ci[p1] = z1i * c1 - z1r * s1;
    float z2r = u0r - u2r, z2i = u0i - u2i;
    cr[p2] = z2r * c2 + z2i * s2; ci[p2] = z2i * c2 - z2r * s2;
    float z3r = u1r - u3i, z3i = u1i + u3r;            // u1 + i*u3
    cr[p3] = z3r * c3 + z3i * s3; ci[p3] = z3i * c3 - z3r * s3;
}

__device__ __forceinline__ void r4_inv(float* cr, float* ci, int j, int h, float ang) {
    int p0 = swz(j), p1 = swz(j + h), p2 = swz(j + 2 * h), p3 = swz(j + 3 * h);
    float z0r = cr[p0], z0i = ci[p0];
    float z1r = cr[p1], z1i = ci[p1];
    float z2r = cr[p2], z2i = ci[p2];
    float z3r = cr[p3], z3i = ci[p3];
    float s1, c1; __sincosf(ang, &s1, &c1);
    float c2 = c1 * c1 - s1 * s1, s2 = 2.f * c1 * s1;
    float c3 = c1 * c2 - s1 * s2, s3 = s1 * c2 + c1 * s2;
    float t1r = z1r * c1 - z1i * s1, t1i = z1i * c1 + z1r * s1;
    float t2r = z2r * c2 - z2i * s2, t2i = z2i * c2 + z2r * s2;
    float t3r = z3r * c3 - z3i * s3, t3i = z3i * c3 + z3r * s3;
    float u0r = z0r + t2r, u0i = z0i + t2i;
    float u1r = z0r - t2r, u1i = z0i - t2i;
    float u2r = t1r + t3r, u2i = t1i + t3i;
    float u3r = t1r - t3r, u3i = t1i - t3i;
    cr[p0] = u0r + u2r; ci[p0] = u0i + u2i;
    cr[p1] = u1r - u3i; ci[p1] = u1i + u3r;            // u1 + i*u3
    cr[p2] = u0r - u2r; ci[p2] = u0i - u2i;
    cr[p3] = u1r + u3i; ci[p3] = u1i - u3r;            // u1 - i*u3
}

// ---- merged: energy transpose (blocks 0..2047) + tf max reduction (blocks 2048..3071)
__global__ __launch_bounds__(256) void k_prep(const float* __restrict__ env,
                                              const float* __restrict__ noise,
                                              const float* __restrict__ tf,
                                              float* __restrict__ ws) {
    __shared__ float tile[256][17];
    int tid = threadIdx.x;
    if (blockIdx.x < 2048) {
        int be = blockIdx.x >> 4;
        int n0 = (blockIdx.x & 15) << 8;
        size_t base = (size_t)be * 65536 + (size_t)n0 * 16;
        float* eT = ws + OFF_ET;
#pragma unroll
        for (int j = 0; j < 16; ++j) {
            int i = tid + j * 256;
            float e = env[base + i];
            float nz = noise[base + i];
            tile[i >> 4][i & 15] = e * (nz * 2.0f - 1.0f);
        }
        __syncthreads();
#pragma unroll
        for (int f = 0; f < 16; ++f)
            eT[(size_t)(be * 16 + f) * 4096 + n0 + tid] = tile[tid][f];
    } else {
        int bb = blockIdx.x - 2048;
        int be = bb >> 3;
        int chunk = bb & 7;
        const float* tfb = tf + (size_t)be * 65568;
        float* red = &tile[0][0];
        int start = chunk * 4098, end = start + 4098;
        float mx = 0.f;
        for (int i = start + tid; i < end; i += 256) {
            int c = i >> 4, f = i & 15;
            float a = tfb[c * 32 + f];
            float b = tfb[c * 32 + 16 + f];
            mx = fmaxf(mx, a * a + b * b);
        }
        red[tid] = mx;
        __syncthreads();
        for (int s = 128; s > 0; s >>= 1) {
            if (tid < s) red[tid] = fmaxf(red[tid], red[tid + s]);
            __syncthreads();
        }
        if (tid == 0) ws[OFF_MAXP + bb] = red[0];
    }
}

// ---- forward FFT of energy frames: E[be][f][k] (unnormalized rfft)
__global__ __launch_bounds__(512) void k_fft_fwd(float* __restrict__ ws) {
    __shared__ float cr[2048], ci[2048];
    int tid = threadIdx.x;
    int be = blockIdx.x >> 4, f = blockIdx.x & 15;
    const float4* src = (const float4*)(ws + OFF_ET) + (size_t)(be * 16 + f) * 1024;
#pragma unroll
    for (int it = 0; it < 2; ++it) {
        int idx = tid + it * 512;
        float4 v = src[idx];
        int n0 = idx * 2;
        cr[swz(n0)] = v.x;     ci[swz(n0)] = v.y;
        cr[swz(n0 + 1)] = v.z; ci[swz(n0 + 1)] = v.w;
    }
    __syncthreads();
#pragma unroll
    for (int it = 0; it < 2; ++it) {                   // radix-2 DIF, h=1024
        int i = tid + it * 512;
        int sj = swz(i), sjb = swz(i + 1024);
        float ar = cr[sj], ai = ci[sj], br = cr[sjb], bi = ci[sjb];
        float dr = ar - br, di = ai - bi;
        float s, c; __sincosf((float)i * (TWO_PI / 2048.0f), &s, &c);
        cr[sj] = ar + br; ci[sj] = ai + bi;
        cr[sjb] = dr * c + di * s; ci[sjb] = di * c - dr * s;
    }
    __syncthreads();
    r4_fwd(cr, ci, (tid >> 8) * 1024 + (tid & 255), 256, (float)(tid & 255) * (TWO_PI / 1024.0f)); __syncthreads();
    r4_fwd(cr, ci, (tid >> 6) * 256 + (tid & 63), 64, (float)(tid & 63) * (TWO_PI / 256.0f)); __syncthreads();
    r4_fwd(cr, ci, (tid & 31) * 64 + (tid >> 5), 16, (float)(tid >> 5) * (TWO_PI / 64.0f)); __syncthreads();
    r4_fwd(cr, ci, (tid & 127) * 16 + (tid >> 7), 4, (float)(tid >> 7) * (TWO_PI / 16.0f)); __syncthreads();
    r4_fwd(cr, ci, tid * 4, 1, 0.0f); __syncthreads();
    float2* Eg = (float2*)(ws + OFF_E) + (size_t)(be * 16 + f) * 2049;
    for (int k = tid; k <= 1024; k += 512) {
        int pk = swz(permf(k));
        int pm = swz(permf((2048 - k) & 2047));
        float zkr = cr[pk], zki = ci[pk], zmr = cr[pm], zmi = ci[pm];
        float xer = 0.5f * (zkr + zmr), xei = 0.5f * (zki - zmi);
        float xor_ = 0.5f * (zki + zmi), xoi = 0.5f * (zmr - zkr);
        float s4, c4; __sincosf((float)k * (TWO_PI / 4096.0f), &s4, &c4);
        float wr = xor_ * c4 + xoi * s4;
        float wi = xoi * c4 - xor_ * s4;
        Eg[k] = make_float2(xer + wr, xei + wi);
        Eg[2048 - k] = make_float2(xer - wr, wi - xei);
    }
}

// ---- per-bin recurrence on pair (k, 2048-k) + fused irfft pre-pack -> Z' natural order
__global__ __launch_bounds__(256) void k_recur(const float* __restrict__ tf,
                                               float* __restrict__ ws) {
    __shared__ float sm2lo[256 * 17], simlo[256 * 17];
    __shared__ float sm2hi[256 * 17], simhi[256 * 17];
    int tid = threadIdx.x;
    int be = blockIdx.y;
    int k0 = blockIdx.x << 8;          // 0,256,512,768
    int hi0 = 1793 - k0;               // hi bins [hi0, hi0+255]
    const float* tfb = tf + (size_t)be * 65568;
    const float4* ab4 = (const float4*)tfb;
    const float4* im4 = (const float4*)(tfb + 32784);

    // stage both bin ranges: m2 = a^2+b^2 and imag (coalesced float4)
    for (int u = tid; u < 2048; u += 256) {
        int half = u >> 10, v = u & 1023;
        int g = v >> 2, e = v & 3;
        int bin = half ? (hi0 + g) : (k0 + g);
        float4 A = ab4[bin * 8 + e];
        float4 Bv = ab4[bin * 8 + e + 4];
        float4 I = im4[bin * 4 + e];
        int o = g * 17 + e * 4;
        float* sm = half ? sm2hi : sm2lo;
        float* si = half ? simhi : simlo;
        sm[o + 0] = A.x * A.x + Bv.x * Bv.x;
        sm[o + 1] = A.y * A.y + Bv.y * Bv.y;
        sm[o + 2] = A.z * A.z + Bv.z * Bv.z;
        sm[o + 3] = A.w * A.w + Bv.w * Bv.w;
        si[o + 0] = I.x; si[o + 1] = I.y; si[o + 2] = I.z; si[o + 3] = I.w;
    }
    __syncthreads();

    int k = k0 + tid;
    int m = 2048 - k;
    int rhi = 255 - tid;
    const float* mp = ws + OFF_MAXP + be * 8;
    float m2x = fmaxf(fmaxf(fmaxf(mp[0], mp[1]), fmaxf(mp[2], mp[3])),
                      fmaxf(fmaxf(mp[4], mp[5]), fmaxf(mp[6], mp[7])));
    float rden = 1.0f / (sqrtf(m2x) + 1e-8f);
    const float2* Eb = (const float2*)(ws + OFF_E) + (size_t)be * 16 * 2049;
    float2* Zb = (float2*)(ws + OFF_Z) + (size_t)be * 16 * 2048;
    float2 evlo[16], evhi[16];
#pragma unroll
    for (int f = 0; f < 16; ++f) {
        evlo[f] = Eb[(size_t)f * 2049 + k];
        evhi[f] = Eb[(size_t)f * 2049 + m];
    }
    float ym = (k == 0) ? 0.0f : 1.0f;   // k==0 pairs with m==2048: both edge bins
    float s4, c4; __sincosf((float)k * (TWO_PI / 4096.0f), &s4, &c4);
    const float SCL = 1.0f / 2048.0f;
    float srl = 0.f, sil = 0.f, srh = 0.f, sih = 0.f;
#pragma unroll
    for (int f = 0; f < 16; ++f) {
        // low bin
        float mh = sqrtf(sm2lo[tid * 17 + f]) * rden;
        float ph = atan2f(simlo[tid * 17 + f], mh) * 3.14159265358979f;
        float sp, cp; __sincosf(ph, &sp, &cp);
        float Tr = mh * cp, Ti = mh * sp;
        sil *= ym;
        srl += evlo[f].x; sil += evlo[f].y;
        float nr = srl * Tr - sil * Ti;
        sil = srl * Ti + sil * Tr; srl = nr;
        // high bin
        float mh2 = sqrtf(sm2hi[rhi * 17 + f]) * rden;
        float ph2 = atan2f(simhi[rhi * 17 + f], mh2) * 3.14159265358979f;
        float sp2, cp2; __sincosf(ph2, &sp2, &cp2);
        float Tr2 = mh2 * cp2, Ti2 = mh2 * sp2;
        sih *= ym;
        srh += evhi[f].x; sih += evhi[f].y;
        float nr2 = srh * Tr2 - sih * Ti2;
        sih = srh * Ti2 + sih * Tr2; srh = nr2;
        // fused irfft pre-pack (SCL folded; output never re-enters state)
        float2* Zf = Zb + (size_t)f * 2048;
        if (k == 0) {
            float y0 = srl * SCL, yn = srh * SCL;
            Zf[0] = make_float2(0.5f * (y0 + yn), 0.5f * (y0 - yn));
        } else {
            float ykr = srl * SCL, yki = sil * SCL;
            float ymr = srh * SCL, ymi = sih * SCL;
            float er = 0.5f * (ykr + ymr), ei = 0.5f * (yki - ymi);
            float dr = ykr - ymr, di = yki + ymi;
            float orr = 0.5f * (dr * c4 - di * s4);
            float oi = 0.5f * (dr * s4 + di * c4);
            Zf[k] = make_float2(er - oi, ei + orr);
            Zf[m] = make_float2(er + oi, orr - ei);
        }
    }
    // bin 1024 (self-paired): one thread, direct global tf reads
    if (k0 == 0 && tid == 0) {
        float sr = 0.f, si = 0.f;
#pragma unroll
        for (int f = 0; f < 16; ++f) {
            float a = tfb[1024 * 32 + f];
            float b = tfb[1024 * 32 + 16 + f];
            float im = tfb[32784 + 1024 * 16 + f];
            float mh = sqrtf(a * a + b * b) * rden;
            float ph = atan2f(im, mh) * 3.14159265358979f;
            float sp, cp; __sincosf(ph, &sp, &cp);
            float Tr = mh * cp, Ti = mh * sp;
            float2 e = Eb[(size_t)f * 2049 + 1024];
            sr += e.x; si += e.y;
            float nr = sr * Tr - si * Ti;
            si = sr * Ti + si * Tr; sr = nr;
            Zb[(size_t)f * 2048 + 1024] = make_float2(sr * SCL, -si * SCL);
        }
    }
}

// ---- inverse FFT: Z'[be][f] (natural order, pre-packed) -> frames [be][f][4096]
__global__ __launch_bounds__(512) void k_fft_inv(float* __restrict__ ws) {
    __shared__ float cr[2048], ci[2048];
    int tid = threadIdx.x;
    int be = blockIdx.x >> 4, f = blockIdx.x & 15;
    const float4* Zg = (const float4*)((float2*)(ws + OFF_Z) + (size_t)(be * 16 + f) * 2048);
#pragma unroll
    for (int it = 0; it < 2; ++it) {
        int idx = tid + it * 512;
        float4 v = Zg[idx];
        int n0 = idx * 2;
        int p0 = swz(permf(n0)), p1 = swz(permf(n0 + 1));
        cr[p0] = v.x; ci[p0] = v.y;
        cr[p1] = v.z; ci[p1] = v.w;
    }
    __syncthreads();
    r4_inv(cr, ci, tid * 4, 1, 0.0f); __syncthreads();
    r4_inv(cr, ci, (tid & 127) * 16 + (tid >> 7), 4, (float)(tid >> 7) * (TWO_PI / 16.0f)); __syncthreads();
    r4_inv(cr, ci, (tid & 31) * 64 + (tid >> 5), 16, (float)(tid >> 5) * (TWO_PI / 64.0f)); __syncthreads();
    r4_inv(cr, ci, (tid >> 6) * 256 + (tid & 63), 64, (float)(tid & 63) * (TWO_PI / 256.0f)); __syncthreads();
    r4_inv(cr, ci, (tid >> 8) * 1024 + (tid & 255), 256, (float)(tid & 255) * (TWO_PI / 1024.0f)); __syncthreads();
#pragma unroll
    for (int it = 0; it < 2; ++it) {                   // radix-2 DIT, h=1024
        int i = tid + it * 512;
        int sj = swz(i), sjb = swz(i + 1024);
        float s, c; __sincosf((float)i * (TWO_PI / 2048.0f), &s, &c);
        float br = cr[sjb], bi = ci[sjb];
        float tr = br * c - bi * s, ti2 = br * s + bi * c;
        float ar = cr[sj], ai = ci[sj];
        cr[sj] = ar + tr;  ci[sj] = ai + ti2;
        cr[sjb] = ar - tr; ci[sjb] = ai - ti2;
    }
    __syncthreads();
    float2* Fg = (float2*)(ws + OFF_ET) + (size_t)(be * 16 + f) * 2048;
#pragma unroll
    for (int it = 0; it < 4; ++it) {
        int m = tid + it * 512;
        Fg[m] = make_float2(cr[swz(m)], ci[swz(m)]);
    }
}

// ---- gather + fused overlap-add (b uniform per block -> scalar indices)
__global__ __launch_bounds__(256) void k_segment(const float* __restrict__ ws,
                                                 const int* __restrict__ indices,
                                                 float* __restrict__ out) {
    __shared__ int ste[16];
    int tid = threadIdx.x;
    int b = blockIdx.y;
    if (tid < 16) ste[tid] = indices[b * 16 + tid] * 256;
    __syncthreads();
    int g = blockIdx.x * 256 + tid;     // float4 index within batch (0..8191)
    int t = g << 2;
    const float* F = ws + OFF_ET;
    float4 acc = make_float4(0.f, 0.f, 0.f, 0.f);
#pragma unroll
    for (int e = 0; e < 16; ++e) {
        int te = ste[e];
        if (t >= te) {
            int d = t - te;
            int j = d >> 11, r = d & 2047;
            size_t base = (size_t)(b * 16 + e) * 65536;
            float4 v = *(const float4*)(F + base + j * 4096 + r);
            acc.x += v.x; acc.y += v.y; acc.z += v.z; acc.w += v.w;
            if (j >= 1) {
                float4 w = *(const float4*)(F + base + (j - 1) * 4096 + 2048 + r);
                acc.x += w.x; acc.y += w.y; acc.z += w.z; acc.w += w.w;
            }
        }
    }
    ((float4*)out)[(size_t)b * 8192 + g] = acc;
}

extern "C" void kernel_launch(void* const* d_in, const int* in_sizes, int n_in,
                              void* d_out, int out_size, void* d_ws, size_t ws_size,
                              hipStream_t stream) {
    const float* env = (const float*)d_in[0];
    const float* tf = (const float*)d_in[1];
    const float* noise = (const float*)d_in[2];
    const int* indices = (const int*)d_in[3];
    float* ws = (float*)d_ws;
    float* out = (float*)d_out;

    k_prep<<<dim3(3072), dim3(256), 0, stream>>>(env, noise, tf, ws);
    k_fft_fwd<<<dim3(2048), dim3(512), 0, stream>>>(ws);
    k_recur<<<dim3(4, 128), dim3(256), 0, stream>>>(tf, ws);
    k_fft_inv<<<dim3(2048), dim3(512), 0, stream>>>(ws);
    k_segment<<<dim3(32, 8), dim3(256), 0, stream>>>(ws, indices, out);
}

// Round 5
// 82.074 us; speedup vs baseline: 1.1365x; 1.1365x over previous
//
#include <hip/hip_runtime.h>
#include <math.h>

#define TWO_PI 6.283185307179586f

// workspace layout (floats)
#define OFF_ET   0ull          // frames [be][f][4096] (inv-FFT output)
#define OFF_E    8388608ull    // spectra E [be][f][2049] float2
#define OFF_MAXP 16781312ull   // 256 partial maxima (2 per be)
#define OFF_Z    16782336ull   // packed Z' [be][f][2048] float2

__device__ __forceinline__ int swz(int n) { return n ^ ((n >> 5) & 31); }

// position of natural index k after DIF with radices [2,4,4,4,4,4]
__device__ __forceinline__ int permf(int k) {
    return ((k & 1) << 10) | (((k >> 1) & 3) << 8) | (((k >> 3) & 3) << 6)
         | (((k >> 5) & 3) << 4) | (((k >> 7) & 3) << 2) | ((k >> 9) & 3);
}

__device__ __forceinline__ void r4_fwd(float* cr, float* ci, int j, int h, float ang) {
    int p0 = swz(j), p1 = swz(j + h), p2 = swz(j + 2 * h), p3 = swz(j + 3 * h);
    float ar = cr[p0], ai = ci[p0];
    float br = cr[p1], bi = ci[p1];
    float crr = cr[p2], cri = ci[p2];
    float drr = cr[p3], dri = ci[p3];
    float u0r = ar + crr, u0i = ai + cri;
    float u1r = ar - crr, u1i = ai - cri;
    float u2r = br + drr, u2i = bi + dri;
    float u3r = br - drr, u3i = bi - dri;
    float s1, c1; __sincosf(ang, &s1, &c1);
    float c2 = c1 * c1 - s1 * s1, s2 = 2.f * c1 * s1;
    float c3 = c1 * c2 - s1 * s2, s3 = s1 * c2 + c1 * s2;
    cr[p0] = u0r + u2r; ci[p0] = u0i + u2i;
    float z1r = u1r + u3i, z1i = u1i - u3r;            // u1 - i*u3
    cr[p1] = z1r * c1 + z1i * s1; ci[p1] = z1i * c1 - z1r * s1;
    float z2r = u0r - u2r, z2i = u0i - u2i;
    cr[p2] = z2r * c2 + z2i * s2; ci[p2] = z2i * c2 - z2r * s2;
    float z3r = u1r - u3i, z3i = u1i + u3r;            // u1 + i*u3
    cr[p3] = z3r * c3 + z3i * s3; ci[p3] = z3i * c3 - z3r * s3;
}

__device__ __forceinline__ void r4_inv(float* cr, float* ci, int j, int h, float ang) {
    int p0 = swz(j), p1 = swz(j + h), p2 = swz(j + 2 * h), p3 = swz(j + 3 * h);
    float z0r = cr[p0], z0i = ci[p0];
    float z1r = cr[p1], z1i = ci[p1];
    float z2r = cr[p2], z2i = ci[p2];
    float z3r = cr[p3], z3i = ci[p3];
    float s1, c1; __sincosf(ang, &s1, &c1);
    float c2 = c1 * c1 - s1 * s1, s2 = 2.f * c1 * s1;
    float c3 = c1 * c2 - s1 * s2, s3 = s1 * c2 + c1 * s2;
    float t1r = z1r * c1 - z1i * s1, t1i = z1i * c1 + z1r * s1;
    float t2r = z2r * c2 - z2i * s2, t2i = z2i * c2 + z2r * s2;
    float t3r = z3r * c3 - z3i * s3, t3i = z3i * c3 + z3r * s3;
    float u0r = z0r + t2r, u0i = z0i + t2i;
    float u1r = z0r - t2r, u1i = z0i - t2i;
    float u2r = t1r + t3r, u2i = t1i + t3i;
    float u3r = t1r - t3r, u3i = t1i - t3i;
    cr[p0] = u0r + u2r; ci[p0] = u0i + u2i;
    cr[p1] = u1r - u3i; ci[p1] = u1i + u3r;            // u1 + i*u3
    cr[p2] = u0r - u2r; ci[p2] = u0i - u2i;
    cr[p3] = u1r + u3i; ci[p3] = u1i - u3r;            // u1 - i*u3
}

// ---- fused: energy + forward FFT (blocks 0..511) | tf max reduction (512..767)
// XCD co-location: the 4 fg-blocks of a be land on one XCD (L2 shares the
// 64B lines that the float4-per-f loads split 4 ways).
__global__ __launch_bounds__(512) void k_fwd(const float* __restrict__ env,
                                             const float* __restrict__ noise,
                                             const float* __restrict__ tf,
                                             float* __restrict__ ws) {
    __shared__ float B[16384];   // 4 FFTs x (cr[2048], ci[2048]) = 64 KB
    int tid = threadIdx.x;
    int id = blockIdx.x;
    if (id < 512) {
        int xcd = id & 7, slot = id >> 3;
        int be = xcd * 16 + (slot >> 2);
        int fg = slot & 3;                       // f = fg*4 .. fg*4+3
        const float4* env4 = (const float4*)env;
        const float4* noi4 = (const float4*)noise;
        size_t base = (size_t)be * 16384 + fg;
        // load + energy + scatter into 4 FFT buffers (swizzled packed order)
        for (int it = 0; it < 8; ++it) {
            int n = it * 512 + tid;
            float4 e = env4[base + (size_t)n * 4];
            float4 z = noi4[base + (size_t)n * 4];
            float v0 = e.x * (z.x * 2.0f - 1.0f);
            float v1 = e.y * (z.y * 2.0f - 1.0f);
            float v2 = e.z * (z.z * 2.0f - 1.0f);
            float v3 = e.w * (z.w * 2.0f - 1.0f);
            int m = swz(n >> 1) + (n & 1) * 2048;   // cr at +0, ci at +2048
            B[m] = v0; B[4096 + m] = v1; B[8192 + m] = v2; B[12288 + m] = v3;
        }
        __syncthreads();
        for (int j = 0; j < 4; ++j) {
            float* cr = B + j * 4096;
            float* ci = cr + 2048;
#pragma unroll
            for (int it = 0; it < 2; ++it) {       // radix-2 DIF, h=1024
                int i = tid + it * 512;
                int sj = swz(i), sjb = swz(i + 1024);
                float ar = cr[sj], ai = ci[sj], br = cr[sjb], bi = ci[sjb];
                float dr = ar - br, di = ai - bi;
                float s, c; __sincosf((float)i * (TWO_PI / 2048.0f), &s, &c);
                cr[sj] = ar + br; ci[sj] = ai + bi;
                cr[sjb] = dr * c + di * s; ci[sjb] = di * c - dr * s;
            }
            __syncthreads();
            r4_fwd(cr, ci, (tid >> 8) * 1024 + (tid & 255), 256, (float)(tid & 255) * (TWO_PI / 1024.0f)); __syncthreads();
            r4_fwd(cr, ci, (tid >> 6) * 256 + (tid & 63), 64, (float)(tid & 63) * (TWO_PI / 256.0f)); __syncthreads();
            r4_fwd(cr, ci, (tid & 31) * 64 + (tid >> 5), 16, (float)(tid >> 5) * (TWO_PI / 64.0f)); __syncthreads();
            r4_fwd(cr, ci, (tid & 127) * 16 + (tid >> 7), 4, (float)(tid >> 7) * (TWO_PI / 16.0f)); __syncthreads();
            r4_fwd(cr, ci, tid * 4, 1, 0.0f); __syncthreads();
            float2* Eg = (float2*)(ws + OFF_E) + (size_t)(be * 16 + fg * 4 + j) * 2049;
            for (int k = tid; k <= 1024; k += 512) {
                int pk = swz(permf(k));
                int pm = swz(permf((2048 - k) & 2047));
                float zkr = cr[pk], zki = ci[pk], zmr = cr[pm], zmi = ci[pm];
                float xer = 0.5f * (zkr + zmr), xei = 0.5f * (zki - zmi);
                float xor_ = 0.5f * (zki + zmi), xoi = 0.5f * (zmr - zkr);
                float s4, c4; __sincosf((float)k * (TWO_PI / 4096.0f), &s4, &c4);
                float wr = xor_ * c4 + xoi * s4;
                float wi = xoi * c4 - xor_ * s4;
                Eg[k] = make_float2(xer + wr, xei + wi);
                Eg[2048 - k] = make_float2(xer - wr, wi - xei);
            }
            __syncthreads();   // before next j reuses nothing, but keep writes ordered
        }
    } else {
        int bb = id - 512;                 // 0..255
        int be = bb >> 1, c = bb & 1;
        const float4* ab4 = (const float4*)(tf + (size_t)be * 65568);
        float mx = 0.f;
        int start = c * 4098, end = start + 4098;   // u = bin*4+e, 2049*4 total
        for (int u = start + tid; u < end; u += 512) {
            int bin = u >> 2, e = u & 3;
            float4 A = ab4[bin * 8 + e];
            float4 Bv = ab4[bin * 8 + e + 4];
            mx = fmaxf(mx, fmaxf(fmaxf(A.x * A.x + Bv.x * Bv.x, A.y * A.y + Bv.y * Bv.y),
                                 fmaxf(A.z * A.z + Bv.z * Bv.z, A.w * A.w + Bv.w * Bv.w)));
        }
        B[tid] = mx;
        __syncthreads();
        for (int s = 256; s > 0; s >>= 1) {
            if (tid < s) B[tid] = fmaxf(B[tid], B[tid + s]);
            __syncthreads();
        }
        if (tid == 0) ws[OFF_MAXP + bb] = B[0];
    }
}

// ---- per-bin recurrence on pair (k, 2048-k) + fused irfft pre-pack -> Z' natural order
__global__ __launch_bounds__(256) void k_recur(const float* __restrict__ tf,
                                               float* __restrict__ ws) {
    __shared__ float sm2lo[256 * 17], simlo[256 * 17];
    __shared__ float sm2hi[256 * 17], simhi[256 * 17];
    int tid = threadIdx.x;
    int be = blockIdx.y;
    int k0 = blockIdx.x << 8;          // 0,256,512,768
    int hi0 = 1793 - k0;               // hi bins [hi0, hi0+255]
    const float* tfb = tf + (size_t)be * 65568;
    const float4* ab4 = (const float4*)tfb;
    const float4* im4 = (const float4*)(tfb + 32784);

    for (int u = tid; u < 2048; u += 256) {
        int half = u >> 10, v = u & 1023;
        int g = v >> 2, e = v & 3;
        int bin = half ? (hi0 + g) : (k0 + g);
        float4 A = ab4[bin * 8 + e];
        float4 Bv = ab4[bin * 8 + e + 4];
        float4 I = im4[bin * 4 + e];
        int o = g * 17 + e * 4;
        float* sm = half ? sm2hi : sm2lo;
        float* si = half ? simhi : simlo;
        sm[o + 0] = A.x * A.x + Bv.x * Bv.x;
        sm[o + 1] = A.y * A.y + Bv.y * Bv.y;
        sm[o + 2] = A.z * A.z + Bv.z * Bv.z;
        sm[o + 3] = A.w * A.w + Bv.w * Bv.w;
        si[o + 0] = I.x; si[o + 1] = I.y; si[o + 2] = I.z; si[o + 3] = I.w;
    }
    __syncthreads();

    int k = k0 + tid;
    int m = 2048 - k;
    int rhi = 255 - tid;
    const float* mp = ws + OFF_MAXP + be * 2;
    float m2x = fmaxf(mp[0], mp[1]);
    float rden = 1.0f / (sqrtf(m2x) + 1e-8f);
    const float2* Eb = (const float2*)(ws + OFF_E) + (size_t)be * 16 * 2049;
    float2* Zb = (float2*)(ws + OFF_Z) + (size_t)be * 16 * 2048;
    float2 evlo[16], evhi[16];
#pragma unroll
    for (int f = 0; f < 16; ++f) {
        evlo[f] = Eb[(size_t)f * 2049 + k];
        evhi[f] = Eb[(size_t)f * 2049 + m];
    }
    float ym = (k == 0) ? 0.0f : 1.0f;
    float s4, c4; __sincosf((float)k * (TWO_PI / 4096.0f), &s4, &c4);
    const float SCL = 1.0f / 2048.0f;
    float srl = 0.f, sil = 0.f, srh = 0.f, sih = 0.f;
#pragma unroll
    for (int f = 0; f < 16; ++f) {
        float mh = sqrtf(sm2lo[tid * 17 + f]) * rden;
        float ph = atan2f(simlo[tid * 17 + f], mh) * 3.14159265358979f;
        float sp, cp; __sincosf(ph, &sp, &cp);
        float Tr = mh * cp, Ti = mh * sp;
        sil *= ym;
        srl += evlo[f].x; sil += evlo[f].y;
        float nr = srl * Tr - sil * Ti;
        sil = srl * Ti + sil * Tr; srl = nr;
        float mh2 = sqrtf(sm2hi[rhi * 17 + f]) * rden;
        float ph2 = atan2f(simhi[rhi * 17 + f], mh2) * 3.14159265358979f;
        float sp2, cp2; __sincosf(ph2, &sp2, &cp2);
        float Tr2 = mh2 * cp2, Ti2 = mh2 * sp2;
        sih *= ym;
        srh += evhi[f].x; sih += evhi[f].y;
        float nr2 = srh * Tr2 - sih * Ti2;
        sih = srh * Ti2 + sih * Tr2; srh = nr2;
        float2* Zf = Zb + (size_t)f * 2048;
        if (k == 0) {
            float y0 = srl * SCL, yn = srh * SCL;
            Zf[0] = make_float2(0.5f * (y0 + yn), 0.5f * (y0 - yn));
        } else {
            float ykr = srl * SCL, yki = sil * SCL;
            float ymr = srh * SCL, ymi = sih * SCL;
            float er = 0.5f * (ykr + ymr), ei = 0.5f * (yki - ymi);
            float dr = ykr - ymr, di = yki + ymi;
            float orr = 0.5f * (dr * c4 - di * s4);
            float oi = 0.5f * (dr * s4 + di * c4);
            Zf[k] = make_float2(er - oi, ei + orr);
            Zf[m] = make_float2(er + oi, orr - ei);
        }
    }
    if (k0 == 0 && tid == 0) {   // bin 1024 (self-paired)
        float sr = 0.f, si = 0.f;
#pragma unroll
        for (int f = 0; f < 16; ++f) {
            float a = tfb[1024 * 32 + f];
            float b = tfb[1024 * 32 + 16 + f];
            float im = tfb[32784 + 1024 * 16 + f];
            float mh = sqrtf(a * a + b * b) * rden;
            float ph = atan2f(im, mh) * 3.14159265358979f;
            float sp, cp; __sincosf(ph, &sp, &cp);
            float Tr = mh * cp, Ti = mh * sp;
            float2 e = Eb[(size_t)f * 2049 + 1024];
            sr += e.x; si += e.y;
            float nr = sr * Tr - si * Ti;
            si = sr * Ti + si * Tr; sr = nr;
            Zb[(size_t)f * 2048 + 1024] = make_float2(sr * SCL, -si * SCL);
        }
    }
}

// ---- inverse FFT: Z'[be][f] (natural order, pre-packed) -> frames [be][f][4096]
__global__ __launch_bounds__(512) void k_fft_inv(float* __restrict__ ws) {
    __shared__ float cr[2048], ci[2048];
    int tid = threadIdx.x;
    int be = blockIdx.x >> 4, f = blockIdx.x & 15;
    const float4* Zg = (const float4*)((float2*)(ws + OFF_Z) + (size_t)(be * 16 + f) * 2048);
#pragma unroll
    for (int it = 0; it < 2; ++it) {
        int idx = tid + it * 512;
        float4 v = Zg[idx];
        int n0 = idx * 2;
        int p0 = swz(permf(n0)), p1 = swz(permf(n0 + 1));
        cr[p0] = v.x; ci[p0] = v.y;
        cr[p1] = v.z; ci[p1] = v.w;
    }
    __syncthreads();
    r4_inv(cr, ci, tid * 4, 1, 0.0f); __syncthreads();
    r4_inv(cr, ci, (tid & 127) * 16 + (tid >> 7), 4, (float)(tid >> 7) * (TWO_PI / 16.0f)); __syncthreads();
    r4_inv(cr, ci, (tid & 31) * 64 + (tid >> 5), 16, (float)(tid >> 5) * (TWO_PI / 64.0f)); __syncthreads();
    r4_inv(cr, ci, (tid >> 6) * 256 + (tid & 63), 64, (float)(tid & 63) * (TWO_PI / 256.0f)); __syncthreads();
    r4_inv(cr, ci, (tid >> 8) * 1024 + (tid & 255), 256, (float)(tid & 255) * (TWO_PI / 1024.0f)); __syncthreads();
#pragma unroll
    for (int it = 0; it < 2; ++it) {                   // radix-2 DIT, h=1024
        int i = tid + it * 512;
        int sj = swz(i), sjb = swz(i + 1024);
        float s, c; __sincosf((float)i * (TWO_PI / 2048.0f), &s, &c);
        float br = cr[sjb], bi = ci[sjb];
        float tr = br * c - bi * s, ti2 = br * s + bi * c;
        float ar = cr[sj], ai = ci[sj];
        cr[sj] = ar + tr;  ci[sj] = ai + ti2;
        cr[sjb] = ar - tr; ci[sjb] = ai - ti2;
    }
    __syncthreads();
    float2* Fg = (float2*)(ws + OFF_ET) + (size_t)(be * 16 + f) * 2048;
#pragma unroll
    for (int it = 0; it < 4; ++it) {
        int m = tid + it * 512;
        Fg[m] = make_float2(cr[swz(m)], ci[swz(m)]);
    }
}

// ---- gather + fused overlap-add (b uniform per block -> scalar indices)
__global__ __launch_bounds__(256) void k_segment(const float* __restrict__ ws,
                                                 const int* __restrict__ indices,
                                                 float* __restrict__ out) {
    __shared__ int ste[16];
    int tid = threadIdx.x;
    int b = blockIdx.y;
    if (tid < 16) ste[tid] = indices[b * 16 + tid] * 256;
    __syncthreads();
    int g = blockIdx.x * 256 + tid;
    int t = g << 2;
    const float* F = ws + OFF_ET;
    float4 acc = make_float4(0.f, 0.f, 0.f, 0.f);
#pragma unroll
    for (int e = 0; e < 16; ++e) {
        int te = ste[e];
        if (t >= te) {
            int d = t - te;
            int j = d >> 11, r = d & 2047;
            size_t base = (size_t)(b * 16 + e) * 65536;
            float4 v = *(const float4*)(F + base + j * 4096 + r);
            acc.x += v.x; acc.y += v.y; acc.z += v.z; acc.w += v.w;
            if (j >= 1) {
                float4 w = *(const float4*)(F + base + (j - 1) * 4096 + 2048 + r);
                acc.x += w.x; acc.y += w.y; acc.z += w.z; acc.w += w.w;
            }
        }
    }
    ((float4*)out)[(size_t)b * 8192 + g] = acc;
}

extern "C" void kernel_launch(void* const* d_in, const int* in_sizes, int n_in,
                              void* d_out, int out_size, void* d_ws, size_t ws_size,
                              hipStream_t stream) {
    const float* env = (const float*)d_in[0];
    const float* tf = (const float*)d_in[1];
    const float* noise = (const float*)d_in[2];
    const int* indices = (const int*)d_in[3];
    float* ws = (float*)d_ws;
    float* out = (float*)d_out;

    k_fwd<<<dim3(768), dim3(512), 0, stream>>>(env, noise, tf, ws);
    k_recur<<<dim3(4, 128), dim3(256), 0, stream>>>(tf, ws);
    k_fft_inv<<<dim3(2048), dim3(512), 0, stream>>>(ws);
    k_segment<<<dim3(32, 8), dim3(256), 0, stream>>>(ws, indices, out);
}